// Round 16
// baseline (2118.519 us; speedup 1.0000x reference)
//
#include <hip/hip_runtime.h>
#include <hip/hip_bf16.h>
#include <cstddef>
#include <cstdint>

#define BB 64
#define TT 1024
#define HH 512
#define II 64
#define OO 8
#define NOISE_STD 0.05f
#define ALPHA 0.2f

#define G_SLICES 16      // blocks (column slices) per clique
#define BT 4             // batches per clique
#define NC (BB/BT)       // 16 cliques
#define K4EXT 160
#define R2STRIDE 328     // r2 row stride in half2 slots

typedef _Float16 half2_t __attribute__((ext_vector_type(2)));
typedef unsigned int uint32;
typedef uint32 uint4_t __attribute__((ext_vector_type(4)));

#if __has_builtin(__builtin_amdgcn_fdot2)
__device__ __forceinline__ float fdot2f(half2_t a, half2_t b, float c) {
    return __builtin_amdgcn_fdot2(a, b, c, false);
}
#else
__device__ __forceinline__ float fdot2f(half2_t a, half2_t b, float c) {
    return c + (float)a[0] * (float)b[0] + (float)a[1] * (float)b[1];
}
#endif

__device__ __forceinline__ half2_t pkrtz(float a, float b) {
    return __builtin_bit_cast(half2_t, __builtin_amdgcn_cvt_pkrtz(a, b));
}

// barrier that waits ONLY on LDS ops (lgkmcnt) — vmem stays in flight
__device__ __forceinline__ void barrier_lgkm() {
    asm volatile("s_waitcnt lgkmcnt(0)" ::: "memory");
    __builtin_amdgcn_s_barrier();
    asm volatile("" ::: "memory");
}

// 16B coherent load at L3 scope — cross-XCD safe
__device__ __forceinline__ uint4_t load4_sc1(const uint32* p) {
    uint4_t v;
    asm volatile("global_load_dwordx4 %0, %1, off sc1\n\t"
                 "s_waitcnt vmcnt(0)"
                 : "=v"(v) : "v"(p) : "memory");
    return v;
}
// 16B load at L2 scope (bypasses L1, reads the XCD-shared L2) — intra-XCD
__device__ __forceinline__ uint4_t load4_sc0(const uint32* p) {
    uint4_t v;
    asm volatile("global_load_dwordx4 %0, %1, off sc0\n\t"
                 "s_waitcnt vmcnt(0)"
                 : "=v"(v) : "v"(p) : "memory");
    return v;
}
// plain store: lands in the XCD-shared (write-back) L2 — intra-XCD publish
__device__ __forceinline__ void store1_plain(uint32* p, uint32 v) {
    asm volatile("global_store_dword %0, %1, off" :: "v"(p), "v"(v) : "memory");
}

__global__ __launch_bounds__(512, 2)
void rnn_clique(const float* __restrict__ input, const float* __restrict__ noise,
                const float* __restrict__ wi, const float* __restrict__ si,
                const float* __restrict__ wrec, const float* __restrict__ bvec,
                const float* __restrict__ wo, const float* __restrict__ so,
                const float* __restrict__ wi_mask, const float* __restrict__ wrec_mask,
                const float* __restrict__ wo_mask, const float* __restrict__ h0,
                uint32* __restrict__ ex, float* __restrict__ out,
                float* __restrict__ traj)
{
    const int tid  = threadIdx.x;
    const int cq   = blockIdx.x & 15;
    const int sl   = blockIdx.x >> 4;
    const int wv   = tid >> 6;
    const int lane = tid & 63;

    __shared__ half2_t w2[K4EXT * 64];       // staging for eff-weights, 40 KB
    __shared__ half2_t r2[2][BT][R2STRIDE];  // parity-double-buffered activations
    __shared__ float   part[BT][8][32];      // per-wave matvec partials
    __shared__ half2_t wo2[256];             // wo_eff column (sl<8)
    __shared__ float   nbuf[3][BT][32];      // noise ring (t%3), fed by waves 4-7
    __shared__ float   hbuf[2][BT][32];      // f32 h for traj store, parity-buffered
    __shared__ int     mode_sh;              // 1 = XCD-local exchange OK

    uint32* aux = ex + (size_t)NC * 2 * BT * HH;   // handshake region

    if (tid == 0) {
        uint32 xcc;
        asm volatile("s_getreg_b32 %0, hwreg(HW_REG_XCC_ID)" : "=s"(xcc));
        xcc &= 0xFFu;
        __hip_atomic_store(aux + cq * 16 + sl, (1u << 16) | xcc,
                           __ATOMIC_RELAXED, __HIP_MEMORY_SCOPE_AGENT);
    }

    // ---------------- stage extended weight slice ----------------
    {
        const int c = tid & 31, kg = tid >> 5;
        const int gc = sl * 32 + c;
        for (int m = 0; m < 10; ++m) {
            int k4 = m * 16 + kg;
            float v[4];
            #pragma unroll
            for (int q = 0; q < 4; ++q) {
                int kap = k4 * 4 + q;
                float x;
                if (kap < HH) {
                    x = fabsf(wrec[(size_t)kap * HH + gc]) * wrec_mask[(size_t)kap * HH + gc];
                } else if (kap < HH + II) {
                    int i = kap - HH;
                    x = wi[(size_t)i * HH + gc] * si[i] * wi_mask[(size_t)i * HH + gc];
                } else if (kap == HH + II) {
                    x = bvec[gc];
                } else {
                    x = 0.f;
                }
                v[q] = x;
            }
            w2[k4 * 64 + c * 2]     = pkrtz(v[0], v[1]);
            w2[k4 * 64 + c * 2 + 1] = pkrtz(v[2], v[3]);
        }
    }
    if (sl < OO && tid < 256) {
        int k2 = tid, o = sl;
        float v0 = wo[(size_t)(2 * k2) * OO + o] * so[o] * wo_mask[(size_t)(2 * k2) * OO + o];
        float v1 = wo[(size_t)(2 * k2 + 1) * OO + o] * so[o] * wo_mask[(size_t)(2 * k2 + 1) * OO + o];
        wo2[k2] = pkrtz(v0, v1);
    }
    if (tid < 128) {                 // r2[0] h-slots from relu(h0)
        int k4 = tid;
        float v0 = fmaxf(h0[4 * k4 + 0], 0.f), v1 = fmaxf(h0[4 * k4 + 1], 0.f);
        float v2 = fmaxf(h0[4 * k4 + 2], 0.f), v3 = fmaxf(h0[4 * k4 + 3], 0.f);
        half2_t p0 = pkrtz(v0, v1), p1 = pkrtz(v2, v3);
        for (int b = 0; b < BT; ++b) { r2[0][b][2 * k4] = p0; r2[0][b][2 * k4 + 1] = p1; }
    }
    if (tid < 8) {                   // bias + pads in BOTH parity buffers
        int par = tid & 1, b = tid >> 1;
        r2[par][b][288] = half2_t{(_Float16)1.f, (_Float16)0.f};
        for (int s = 289; s < R2STRIDE; ++s) r2[par][b][s] = half2_t{(_Float16)0.f, (_Float16)0.f};
    }

    // persistent per-lane state: finalize lanes (waves 0-3, lanes<32)
    float h_st = 0.f;
    float* trajp = nullptr;
    uint32* exw = nullptr;
    if (wv < BT && lane < 32) {
        int b = wv, gc = sl * 32 + lane, bg = cq * BT + b;
        h_st  = h0[gc];
        trajp = traj + (size_t)bg * (TT + 1) * HH;
        trajp[gc] = h_st;                                // trajectories[:,0,:]
        exw = ex + (size_t)(cq * 2 * BT + b) * HH + gc;
    }
    // vmem-service lanes (waves 4-7, lanes<32): noise/x/traj per batch b=wv-4
    const float* noisepb = nullptr;
    const float* xbase = nullptr;
    float* trajpb = nullptr;
    int gcw = sl * 32 + (lane & 31);
    if (wv >= 4 && lane < 32) {
        int b = wv - 4, bg = cq * BT + b;
        noisepb = noise + (size_t)bg * TT * HH;
        xbase   = input + (size_t)bg * TT * II;
        trajpb  = traj + (size_t)bg * (TT + 1) * HH;
        nbuf[0][b][lane] = noisepb[gcw];                 // noise(0)
        nbuf[1][b][lane] = noisepb[(size_t)HH + gcw];    // noise(1)
        const float* xp = xbase;                         // x(0)
        r2[0][b][256 + lane] = pkrtz(xp[2 * lane], xp[2 * lane + 1]);
    }
    __syncthreads();

    const int c_    = lane & 31;
    const int shalf = lane >> 5;
    const int seg   = wv * 2 + shalf;          // 0..15

    // ---- hoist this thread's weights into registers (20 half2) ----
    half2_t wr[5][4];
    #pragma unroll
    for (int ch = 0; ch < 5; ++ch) {
        int k4b = seg * 10 + ch * 2;
        wr[ch][0] = w2[k4b * 64 + c_ * 2];
        wr[ch][1] = w2[k4b * 64 + c_ * 2 + 1];
        wr[ch][2] = w2[(k4b + 1) * 64 + c_ * 2];
        wr[ch][3] = w2[(k4b + 1) * 64 + c_ * 2 + 1];
    }

    // ---- collect the clique's XCD ids; uniform -> L2-local fast path ----
    if (wv == 0) {
        uint32 v = (1u << 16);
        for (;;) {
            if (lane < 16)
                v = __hip_atomic_load(aux + cq * 16 + lane,
                                      __ATOMIC_RELAXED, __HIP_MEMORY_SCOPE_AGENT);
            if (__ballot((v >> 16) == 1u) == ~0ull) break;
            __builtin_amdgcn_s_sleep(1);
        }
        uint32 myx = v & 0xFFFFu;
        uint32 x0  = __shfl(myx, 0);
        bool eq = (lane < 16) ? (myx == x0) : true;
        if (lane == 0) mode_sh = (__ballot(eq) == ~0ull) ? 1 : 0;
    }
    __syncthreads();
    const bool local_mode = (mode_sh != 0);

    // gather mapping: thread covers 4 consecutive columns (one dwordx4)
    const int gb  = tid >> 7;
    const int k4g = tid & 127;
    uint32* exg0 = ex + (size_t)(cq * 2 * BT + gb) * HH + (size_t)(4 * k4g);
    const size_t expar = (size_t)BT * HH;

    for (int t = 0; t < TT; ++t) {
        const int p = t & 1;

        // ---- early vmem issue by SERVICE waves only (complete under matvec) ----
        float nfly = 0.f, xa = 0.f, xb = 0.f;
        if (wv >= 4 && lane < 32) {
            int tn2 = (t + 2 < TT) ? (t + 2) : (TT - 1);
            nfly = noisepb[(size_t)tn2 * HH + gcw];               // noise(t+2)
            int tn1 = (t + 1 < TT) ? (t + 1) : (TT - 1);
            const float* xp = xbase + (size_t)tn1 * II;
            xa = xp[2 * lane]; xb = xp[2 * lane + 1];             // x(t+1)
        }

        // ---- matvec from r2[p] with register weights (all 8 waves) ----
        float acc0 = 0.f, acc1 = 0.f, acc2 = 0.f, acc3 = 0.f;
        #pragma unroll
        for (int ch = 0; ch < 5; ++ch) {
            int k2b = seg * 20 + ch * 4;
            {
                half2_t ra = r2[p][0][k2b], rb = r2[p][0][k2b + 1], rc = r2[p][0][k2b + 2], rd = r2[p][0][k2b + 3];
                acc0 = fdot2f(ra, wr[ch][0], acc0); acc0 = fdot2f(rb, wr[ch][1], acc0);
                acc0 = fdot2f(rc, wr[ch][2], acc0); acc0 = fdot2f(rd, wr[ch][3], acc0);
            }
            {
                half2_t ra = r2[p][1][k2b], rb = r2[p][1][k2b + 1], rc = r2[p][1][k2b + 2], rd = r2[p][1][k2b + 3];
                acc1 = fdot2f(ra, wr[ch][0], acc1); acc1 = fdot2f(rb, wr[ch][1], acc1);
                acc1 = fdot2f(rc, wr[ch][2], acc1); acc1 = fdot2f(rd, wr[ch][3], acc1);
            }
            {
                half2_t ra = r2[p][2][k2b], rb = r2[p][2][k2b + 1], rc = r2[p][2][k2b + 2], rd = r2[p][2][k2b + 3];
                acc2 = fdot2f(ra, wr[ch][0], acc2); acc2 = fdot2f(rb, wr[ch][1], acc2);
                acc2 = fdot2f(rc, wr[ch][2], acc2); acc2 = fdot2f(rd, wr[ch][3], acc2);
            }
            {
                half2_t ra = r2[p][3][k2b], rb = r2[p][3][k2b + 1], rc = r2[p][3][k2b + 2], rd = r2[p][3][k2b + 3];
                acc3 = fdot2f(ra, wr[ch][0], acc3); acc3 = fdot2f(rb, wr[ch][1], acc3);
                acc3 = fdot2f(rc, wr[ch][2], acc3); acc3 = fdot2f(rd, wr[ch][3], acc3);
            }
        }
        acc0 += __shfl_xor(acc0, 32);
        acc1 += __shfl_xor(acc1, 32);
        acc2 += __shfl_xor(acc2, 32);
        acc3 += __shfl_xor(acc3, 32);
        if (shalf == 0) {
            part[0][wv][c_] = acc0;
            part[1][wv][c_] = acc1;
            part[2][wv][c_] = acc2;
            part[3][wv][c_] = acc3;
        }
        barrier_lgkm();   // B1 — LDS fence only; service-wave loads stay in flight

        const uint32 tag = (uint32)(t + 2);      // tag for h(t+1); memset-0 never matches
        const size_t poff = (size_t)p * expar;   // h(t+1) parity

        if (wv < BT && lane < 32) {
            // ---- finalize + publish: the ONLY vmem store these waves issue ----
            int b = wv;
            float mv = 0.f;
            #pragma unroll
            for (int m = 0; m < 8; ++m) mv += part[b][m][c_];
            float hn = (1.f - ALPHA) * h_st + ALPHA * mv + NOISE_STD * nbuf[t % 3][b][lane];
            h_st = hn;
            uint32 r16 = __builtin_bit_cast(uint32,
                           __builtin_amdgcn_cvt_pkrtz(fmaxf(hn, 0.f), 0.f)) & 0xFFFFu;
            uint32 word = (tag << 16) | r16;
            if (local_mode) {
                store1_plain(exw + poff, word);
            } else {
                __hip_atomic_store(exw + poff, word,
                                   __ATOMIC_RELAXED, __HIP_MEMORY_SCOPE_AGENT);
            }
            hbuf[p ^ 1][b][lane] = hn;           // f32 h for deferred traj store
        }

        // ---- gather h(t+1) -> r2[p^1] (all threads) ----
        {
            const uint32* g0 = exg0 + poff;
            uint4_t w;
            int spins = 0;
            if (local_mode) {
                for (;;) {
                    w = load4_sc0(g0);
                    if ((w[0] >> 16) == tag && (w[1] >> 16) == tag &&
                        (w[2] >> 16) == tag && (w[3] >> 16) == tag) break;
                    if (++spins > 8) __builtin_amdgcn_s_sleep(1);
                }
            } else {
                for (;;) {
                    w = load4_sc1(g0);
                    if ((w[0] >> 16) == tag && (w[1] >> 16) == tag &&
                        (w[2] >> 16) == tag && (w[3] >> 16) == tag) break;
                    __builtin_amdgcn_s_sleep(1);
                }
            }
            uint32 q0 = (w[0] & 0xFFFFu) | (w[1] << 16);
            uint32 q1 = (w[2] & 0xFFFFu) | (w[3] << 16);
            r2[p ^ 1][gb][2 * k4g]     = __builtin_bit_cast(half2_t, q0);
            r2[p ^ 1][gb][2 * k4g + 1] = __builtin_bit_cast(half2_t, q1);
        }

        // ---- service waves: out-proj + x-stage + nbuf + traj (post-gather) ----
        if (wv >= 4) {
            if (sl < OO && t > 0) {
                int b = wv - 4;
                int k2 = lane * 4;
                float q = 0.f;
                q = fdot2f(r2[p][b][k2],     wo2[k2],     q);
                q = fdot2f(r2[p][b][k2 + 1], wo2[k2 + 1], q);
                q = fdot2f(r2[p][b][k2 + 2], wo2[k2 + 2], q);
                q = fdot2f(r2[p][b][k2 + 3], wo2[k2 + 3], q);
                #pragma unroll
                for (int d = 32; d >= 1; d >>= 1) q += __shfl_xor(q, d);
                if (lane == 0) out[((size_t)(cq * BT + (wv - 4)) * TT + (t - 1)) * OO + sl] = q;
            }
            if (lane < 32) {
                int b = wv - 4;
                r2[p ^ 1][b][256 + lane] = pkrtz(xa, xb);        // x(t+1)
                nbuf[(t + 2) % 3][b][lane] = nfly;               // noise(t+2)
                if (t > 0)                                       // traj(t) = h(t)
                    trajpb[(size_t)t * HH + gcw] = hbuf[p][b][lane];
            }
        }
        barrier_lgkm();   // B2 — r2[p^1]/nbuf/hbuf consumed-produced; vmem in flight
    }

    // ---- epilogue ----
    if (wv >= 4 && lane < 32) {      // traj[TT] = h(TT) from hbuf[0]
        int b = wv - 4;
        trajpb[(size_t)TT * HH + gcw] = hbuf[0][b][lane];
    }
    if (wv >= 4 && sl < OO) {        // out(TT-1) from r2[0] = relu(h(TT))
        int b = wv - 4;
        int k2 = lane * 4;
        float q = 0.f;
        q = fdot2f(r2[0][b][k2],     wo2[k2],     q);
        q = fdot2f(r2[0][b][k2 + 1], wo2[k2 + 1], q);
        q = fdot2f(r2[0][b][k2 + 2], wo2[k2 + 2], q);
        q = fdot2f(r2[0][b][k2 + 3], wo2[k2 + 3], q);
        #pragma unroll
        for (int d = 32; d >= 1; d >>= 1) q += __shfl_xor(q, d);
        if (lane == 0) out[((size_t)(cq * BT + b) * TT + (TT - 1)) * OO + sl] = q;
    }
}

// ---------------- host launcher ----------------
extern "C" void kernel_launch(void* const* d_in, const int* in_sizes, int n_in,
                              void* d_out, int out_size, void* d_ws, size_t ws_size,
                              hipStream_t stream) {
    const float* input     = (const float*)d_in[0];
    const float* noise     = (const float*)d_in[1];
    const float* wi        = (const float*)d_in[2];
    const float* si        = (const float*)d_in[3];
    const float* wrec      = (const float*)d_in[4];
    const float* bvec      = (const float*)d_in[5];
    const float* wo        = (const float*)d_in[6];
    const float* so        = (const float*)d_in[7];
    const float* wi_mask   = (const float*)d_in[8];
    const float* wrec_mask = (const float*)d_in[9];
    const float* wo_mask   = (const float*)d_in[10];
    const float* h0        = (const float*)d_in[11];

    float* out  = (float*)d_out;
    float* traj = out + (size_t)BB * TT * OO;
    uint32* ex  = (uint32*)d_ws;

    // clear exchange + handshake tags every call (stale-tag safety; replay-safe)
    (void)hipMemsetAsync(d_ws, 0,
        (size_t)(NC * 2 * BT * HH + NC * G_SLICES) * sizeof(uint32), stream);

    rnn_clique<<<dim3(NC * G_SLICES), dim3(512), 0, stream>>>(
        input, noise, wi, si, wrec, bvec, wo, so,
        wi_mask, wrec_mask, wo_mask, h0, ex, out, traj);
}

// Round 17
// 1597.900 us; speedup vs baseline: 1.3258x; 1.3258x over previous
//
#include <hip/hip_runtime.h>
#include <hip/hip_bf16.h>
#include <cstddef>
#include <cstdint>

#define BB 64
#define TT 1024
#define HH 512
#define II 64
#define OO 8
#define NOISE_STD 0.05f
#define ALPHA 0.2f

#define G_SLICES 16      // blocks (column slices) per clique
#define BT 4             // batches per clique
#define NC (BB/BT)       // 16 cliques
#define K4EXT 160
#define R2STRIDE 328     // r2 row stride in half2 slots

typedef _Float16 half2_t __attribute__((ext_vector_type(2)));
typedef unsigned int uint32;
typedef uint32 uint4_t __attribute__((ext_vector_type(4)));

#if __has_builtin(__builtin_amdgcn_fdot2)
__device__ __forceinline__ float fdot2f(half2_t a, half2_t b, float c) {
    return __builtin_amdgcn_fdot2(a, b, c, false);
}
#else
__device__ __forceinline__ float fdot2f(half2_t a, half2_t b, float c) {
    return c + (float)a[0] * (float)b[0] + (float)a[1] * (float)b[1];
}
#endif

__device__ __forceinline__ half2_t pkrtz(float a, float b) {
    return __builtin_bit_cast(half2_t, __builtin_amdgcn_cvt_pkrtz(a, b));
}

// 16B coherent load at L3 scope (bypasses non-coherent local L2) — cross-XCD safe
__device__ __forceinline__ uint4_t load4_sc1(const uint32* p) {
    uint4_t v;
    asm volatile("global_load_dwordx4 %0, %1, off sc1\n\t"
                 "s_waitcnt vmcnt(0)"
                 : "=v"(v) : "v"(p) : "memory");
    return v;
}
// 16B load at L2 scope (bypasses L1, reads the XCD-shared L2) — intra-XCD
__device__ __forceinline__ uint4_t load4_sc0(const uint32* p) {
    uint4_t v;
    asm volatile("global_load_dwordx4 %0, %1, off sc0\n\t"
                 "s_waitcnt vmcnt(0)"
                 : "=v"(v) : "v"(p) : "memory");
    return v;
}
// plain store: lands in the XCD-shared (write-back) L2 — intra-XCD publish
__device__ __forceinline__ void store1_plain(uint32* p, uint32 v) {
    asm volatile("global_store_dword %0, %1, off" :: "v"(p), "v"(v) : "memory");
}

__global__ __launch_bounds__(512, 2)
void rnn_clique(const float* __restrict__ input, const float* __restrict__ noise,
                const float* __restrict__ wi, const float* __restrict__ si,
                const float* __restrict__ wrec, const float* __restrict__ bvec,
                const float* __restrict__ wo, const float* __restrict__ so,
                const float* __restrict__ wi_mask, const float* __restrict__ wrec_mask,
                const float* __restrict__ wo_mask, const float* __restrict__ h0,
                uint32* __restrict__ ex, float* __restrict__ out,
                float* __restrict__ traj)
{
    const int tid  = threadIdx.x;
    // clique = bid mod 16 -> all 16 blocks of a clique share bid mod 8
    // -> same XCD under round-robin dispatch (verified at runtime)
    const int cq   = blockIdx.x & 15;
    const int sl   = blockIdx.x >> 4;
    const int wv   = tid >> 6;
    const int lane = tid & 63;

    __shared__ half2_t w2[K4EXT * 64];       // staging for eff-weights, 40 KB
    __shared__ half2_t r2[2][BT][R2STRIDE];  // parity-double-buffered activations
    __shared__ float   part[BT][8][32];      // per-wave matvec partials
    __shared__ half2_t wo2[256];             // wo_eff column (sl<8)
    __shared__ int     mode_sh;              // 1 = XCD-local exchange OK

    uint32* aux = ex + (size_t)NC * 2 * BT * HH;   // handshake region

    if (tid == 0) {
        uint32 xcc;
        asm volatile("s_getreg_b32 %0, hwreg(HW_REG_XCC_ID)" : "=s"(xcc));
        xcc &= 0xFFu;
        __hip_atomic_store(aux + cq * 16 + sl, (1u << 16) | xcc,
                           __ATOMIC_RELAXED, __HIP_MEMORY_SCOPE_AGENT);
    }

    // ---------------- stage extended weight slice ----------------
    {
        const int c = tid & 31, kg = tid >> 5;
        const int gc = sl * 32 + c;
        for (int m = 0; m < 10; ++m) {
            int k4 = m * 16 + kg;
            float v[4];
            #pragma unroll
            for (int q = 0; q < 4; ++q) {
                int kap = k4 * 4 + q;
                float x;
                if (kap < HH) {
                    x = fabsf(wrec[(size_t)kap * HH + gc]) * wrec_mask[(size_t)kap * HH + gc];
                } else if (kap < HH + II) {
                    int i = kap - HH;
                    x = wi[(size_t)i * HH + gc] * si[i] * wi_mask[(size_t)i * HH + gc];
                } else if (kap == HH + II) {
                    x = bvec[gc];
                } else {
                    x = 0.f;
                }
                v[q] = x;
            }
            w2[k4 * 64 + c * 2]     = pkrtz(v[0], v[1]);
            w2[k4 * 64 + c * 2 + 1] = pkrtz(v[2], v[3]);
        }
    }
    if (sl < OO && tid < 256) {
        int k2 = tid, o = sl;
        float v0 = wo[(size_t)(2 * k2) * OO + o] * so[o] * wo_mask[(size_t)(2 * k2) * OO + o];
        float v1 = wo[(size_t)(2 * k2 + 1) * OO + o] * so[o] * wo_mask[(size_t)(2 * k2 + 1) * OO + o];
        wo2[k2] = pkrtz(v0, v1);
    }
    if (tid < 128) {                 // r2[0] h-slots from relu(h0)
        int k4 = tid;
        float v0 = fmaxf(h0[4 * k4 + 0], 0.f), v1 = fmaxf(h0[4 * k4 + 1], 0.f);
        float v2 = fmaxf(h0[4 * k4 + 2], 0.f), v3 = fmaxf(h0[4 * k4 + 3], 0.f);
        half2_t p0 = pkrtz(v0, v1), p1 = pkrtz(v2, v3);
        for (int b = 0; b < BT; ++b) { r2[0][b][2 * k4] = p0; r2[0][b][2 * k4 + 1] = p1; }
    }
    if (tid < 8) {                   // bias + pads in BOTH parity buffers
        int par = tid & 1, b = tid >> 1;
        r2[par][b][288] = half2_t{(_Float16)1.f, (_Float16)0.f};
        for (int s = 289; s < R2STRIDE; ++s) r2[par][b][s] = half2_t{(_Float16)0.f, (_Float16)0.f};
    }
    if (wv >= 4 && lane < 32) {      // x(0) into r2[0]
        int b = wv - 4, i2 = lane;
        const float* xp = input + ((size_t)(cq * BT + b) * TT + 0) * II + 2 * i2;
        r2[0][b][256 + i2] = pkrtz(xp[0], xp[1]);
    }

    // persistent per-lane state for finalize lanes
    float h_st = 0.f, n_reg = 0.f, n_reg2 = 0.f;
    float* trajp = nullptr;
    const float* noisep = nullptr;
    uint32* exw = nullptr;
    if (wv < BT && lane < 32) {
        int b = wv, c = lane, gc = sl * 32 + c, bg = cq * BT + b;
        h_st   = h0[gc];
        noisep = noise + (size_t)bg * TT * HH;
        trajp  = traj + (size_t)bg * (TT + 1) * HH;
        n_reg  = noisep[gc];                 // noise[b][0][gc]
        n_reg2 = noisep[(size_t)HH + gc];    // noise[b][1][gc]
        trajp[gc] = h_st;
        exw = ex + (size_t)(cq * 2 * BT + b) * HH + gc;
    }
    __syncthreads();

    const int c_    = lane & 31;
    const int shalf = lane >> 5;
    const int seg   = wv * 2 + shalf;          // 0..15

    // ---- hoist this thread's weights into registers (20 half2) ----
    half2_t wr[5][4];
    #pragma unroll
    for (int ch = 0; ch < 5; ++ch) {
        int k4b = seg * 10 + ch * 2;
        wr[ch][0] = w2[k4b * 64 + c_ * 2];
        wr[ch][1] = w2[k4b * 64 + c_ * 2 + 1];
        wr[ch][2] = w2[(k4b + 1) * 64 + c_ * 2];
        wr[ch][3] = w2[(k4b + 1) * 64 + c_ * 2 + 1];
    }

    // ---- collect the clique's XCD ids; uniform -> L2-local fast path ----
    if (wv == 0) {
        uint32 v = (1u << 16);
        for (;;) {
            if (lane < 16)
                v = __hip_atomic_load(aux + cq * 16 + lane,
                                      __ATOMIC_RELAXED, __HIP_MEMORY_SCOPE_AGENT);
            if (__ballot((v >> 16) == 1u) == ~0ull) break;
            __builtin_amdgcn_s_sleep(1);
        }
        uint32 myx = v & 0xFFFFu;
        uint32 x0  = __shfl(myx, 0);
        bool eq = (lane < 16) ? (myx == x0) : true;
        if (lane == 0) mode_sh = (__ballot(eq) == ~0ull) ? 1 : 0;
    }
    __syncthreads();
    const bool local_mode = (mode_sh != 0);

    // gather mapping: thread covers 4 consecutive columns (one dwordx4)
    const int gb  = tid >> 7;
    const int k4g = tid & 127;
    uint32* exg0 = ex + (size_t)(cq * 2 * BT + gb) * HH + (size_t)(4 * k4g);
    const size_t expar = (size_t)BT * HH;

    for (int t = 0; t < TT; ++t) {
        const int p = t & 1;

        // ---- matvec from r2[p] with register weights ----
        float acc0 = 0.f, acc1 = 0.f, acc2 = 0.f, acc3 = 0.f;
        #pragma unroll
        for (int ch = 0; ch < 5; ++ch) {
            int k2b = seg * 20 + ch * 4;
            {
                half2_t ra = r2[p][0][k2b], rb = r2[p][0][k2b + 1], rc = r2[p][0][k2b + 2], rd = r2[p][0][k2b + 3];
                acc0 = fdot2f(ra, wr[ch][0], acc0); acc0 = fdot2f(rb, wr[ch][1], acc0);
                acc0 = fdot2f(rc, wr[ch][2], acc0); acc0 = fdot2f(rd, wr[ch][3], acc0);
            }
            {
                half2_t ra = r2[p][1][k2b], rb = r2[p][1][k2b + 1], rc = r2[p][1][k2b + 2], rd = r2[p][1][k2b + 3];
                acc1 = fdot2f(ra, wr[ch][0], acc1); acc1 = fdot2f(rb, wr[ch][1], acc1);
                acc1 = fdot2f(rc, wr[ch][2], acc1); acc1 = fdot2f(rd, wr[ch][3], acc1);
            }
            {
                half2_t ra = r2[p][2][k2b], rb = r2[p][2][k2b + 1], rc = r2[p][2][k2b + 2], rd = r2[p][2][k2b + 3];
                acc2 = fdot2f(ra, wr[ch][0], acc2); acc2 = fdot2f(rb, wr[ch][1], acc2);
                acc2 = fdot2f(rc, wr[ch][2], acc2); acc2 = fdot2f(rd, wr[ch][3], acc2);
            }
            {
                half2_t ra = r2[p][3][k2b], rb = r2[p][3][k2b + 1], rc = r2[p][3][k2b + 2], rd = r2[p][3][k2b + 3];
                acc3 = fdot2f(ra, wr[ch][0], acc3); acc3 = fdot2f(rb, wr[ch][1], acc3);
                acc3 = fdot2f(rc, wr[ch][2], acc3); acc3 = fdot2f(rd, wr[ch][3], acc3);
            }
        }
        acc0 += __shfl_xor(acc0, 32);
        acc1 += __shfl_xor(acc1, 32);
        acc2 += __shfl_xor(acc2, 32);
        acc3 += __shfl_xor(acc3, 32);
        if (shalf == 0) {
            part[0][wv][c_] = acc0;
            part[1][wv][c_] = acc1;
            part[2][wv][c_] = acc2;
            part[3][wv][c_] = acc3;
        }
        __syncthreads();   // B1

        const uint32 tag = (uint32)(t + 2);      // tag for h(t+1); memset-0 never matches
        const size_t poff = (size_t)p * expar;   // h(t+1) lives at parity t&1

        if (wv < BT && lane < 32) {
            // ---- finalize + publish ----
            int b = wv, c = lane, gc = sl * 32 + c;
            float mv = 0.f;
            #pragma unroll
            for (int m = 0; m < 8; ++m) mv += part[b][m][c];
            float hn = (1.f - ALPHA) * h_st + ALPHA * mv + NOISE_STD * n_reg;
            h_st = hn;
            uint32 r16 = __builtin_bit_cast(uint32,
                           __builtin_amdgcn_cvt_pkrtz(fmaxf(hn, 0.f), 0.f)) & 0xFFFFu;
            uint32 word = (tag << 16) | r16;
            if (local_mode) {
                store1_plain(exw + poff, word);
            } else {
                __hip_atomic_store(exw + poff, word,
                                   __ATOMIC_RELAXED, __HIP_MEMORY_SCOPE_AGENT);
            }
            trajp[(size_t)(t + 1) * HH + gc] = hn;
            n_reg = n_reg2;
            int tn = (t + 2 < TT) ? (t + 2) : (TT - 1);
            n_reg2 = noisep[(size_t)tn * HH + gc];
        } else if (wv >= 4) {
            if (sl < OO && t > 0) {
                // out(t-1) = relu(h(t)) . wo  from r2[p]
                int b = wv - 4;
                int k2 = lane * 4;
                float q = 0.f;
                q = fdot2f(r2[p][b][k2],     wo2[k2],     q);
                q = fdot2f(r2[p][b][k2 + 1], wo2[k2 + 1], q);
                q = fdot2f(r2[p][b][k2 + 2], wo2[k2 + 2], q);
                q = fdot2f(r2[p][b][k2 + 3], wo2[k2 + 3], q);
                #pragma unroll
                for (int d = 32; d >= 1; d >>= 1) q += __shfl_xor(q, d);
                if (lane == 0) out[((size_t)(cq * BT + b) * TT + (t - 1)) * OO + sl] = q;
            }
            if (lane < 32) {          // stage x(t+1) into r2[p^1]
                int b = wv - 4, i2 = lane;
                int tn = (t + 1 < TT) ? (t + 1) : (TT - 1);
                const float* xp = input + ((size_t)(cq * BT + b) * TT + tn) * II + 2 * i2;
                r2[p ^ 1][b][256 + i2] = pkrtz(xp[0], xp[1]);
            }
        }

        // ---- gather h(t+1) -> r2[p^1] (all threads; overlaps with above) ----
        {
            const uint32* g0 = exg0 + poff;
            uint4_t w;
            int spins = 0;
            if (local_mode) {
                for (;;) {
                    w = load4_sc0(g0);
                    if ((w[0] >> 16) == tag && (w[1] >> 16) == tag &&
                        (w[2] >> 16) == tag && (w[3] >> 16) == tag) break;
                    if (++spins > 8) __builtin_amdgcn_s_sleep(1);
                }
            } else {
                for (;;) {
                    w = load4_sc1(g0);
                    if ((w[0] >> 16) == tag && (w[1] >> 16) == tag &&
                        (w[2] >> 16) == tag && (w[3] >> 16) == tag) break;
                    __builtin_amdgcn_s_sleep(1);
                }
            }
            uint32 q0 = (w[0] & 0xFFFFu) | (w[1] << 16);
            uint32 q1 = (w[2] & 0xFFFFu) | (w[3] << 16);
            r2[p ^ 1][gb][2 * k4g]     = __builtin_bit_cast(half2_t, q0);
            r2[p ^ 1][gb][2 * k4g + 1] = __builtin_bit_cast(half2_t, q1);
        }
        __syncthreads();   // B2 (r2[p^1] ready; part[] consumed)
    }

    // ---- epilogue: out(TT-1) from r2[0] = relu(h(TT)) ----
    if (wv >= 4 && sl < OO) {
        int b = wv - 4;
        int k2 = lane * 4;
        float q = 0.f;
        q = fdot2f(r2[0][b][k2],     wo2[k2],     q);
        q = fdot2f(r2[0][b][k2 + 1], wo2[k2 + 1], q);
        q = fdot2f(r2[0][b][k2 + 2], wo2[k2 + 2], q);
        q = fdot2f(r2[0][b][k2 + 3], wo2[k2 + 3], q);
        #pragma unroll
        for (int d = 32; d >= 1; d >>= 1) q += __shfl_xor(q, d);
        if (lane == 0) out[((size_t)(cq * BT + b) * TT + (TT - 1)) * OO + sl] = q;
    }
}

// ---------------- host launcher ----------------
extern "C" void kernel_launch(void* const* d_in, const int* in_sizes, int n_in,
                              void* d_out, int out_size, void* d_ws, size_t ws_size,
                              hipStream_t stream) {
    const float* input     = (const float*)d_in[0];
    const float* noise     = (const float*)d_in[1];
    const float* wi        = (const float*)d_in[2];
    const float* si        = (const float*)d_in[3];
    const float* wrec      = (const float*)d_in[4];
    const float* bvec      = (const float*)d_in[5];
    const float* wo        = (const float*)d_in[6];
    const float* so        = (const float*)d_in[7];
    const float* wi_mask   = (const float*)d_in[8];
    const float* wrec_mask = (const float*)d_in[9];
    const float* wo_mask   = (const float*)d_in[10];
    const float* h0        = (const float*)d_in[11];

    float* out  = (float*)d_out;
    float* traj = out + (size_t)BB * TT * OO;
    uint32* ex  = (uint32*)d_ws;

    // clear exchange + handshake tags every call (stale-tag safety; replay-safe)
    (void)hipMemsetAsync(d_ws, 0,
        (size_t)(NC * 2 * BT * HH + NC * G_SLICES) * sizeof(uint32), stream);

    rnn_clique<<<dim3(NC * G_SLICES), dim3(512), 0, stream>>>(
        input, noise, wi, si, wrec, bvec, wo, so,
        wi_mask, wrec_mask, wo_mask, h0, ex, out, traj);
}